// Round 1
// baseline (75.149 us; speedup 1.0000x reference)
//
#include <hip/hip_runtime.h>
#include <hip/hip_bf16.h>
#include <math.h>

// Problem constants (fixed by setup_inputs in the reference):
//   features: [B=2, C=512, H=50, W=64] float32
//   roiss:    [B=2, N=128, 4]          float32  (x1,y1,x2,y2 pixel coords)
//   out:      [B, N, C]                float32
#define IMG_W_F 1024.0f
#define IMG_H_F 800.0f

__global__ __launch_bounds__(256) void roipool_kernel(
    const float* __restrict__ feat,   // [B, C, H, W]
    const float* __restrict__ rois,   // [B, N, 4]
    float* __restrict__ out,          // [B, N, C]
    int B, int C, int H, int W, int N)
{
    const int bn = blockIdx.x;            // b * N + n
    const int b  = bn / N;

    // Load ROI (all threads read the same 4 floats; L1-broadcast, cheap).
    const float* roi = rois + (size_t)bn * 4;
    const float rx1 = roi[0], ry1 = roi[1], rx2 = roi[2], ry2 = roi[3];

    // Replicate reference math exactly: divide by image dim, multiply by
    // feature dim (same op order as numpy/JAX fp32), floor/ceil, cast,
    // clip min 0.
    int x1 = (int)floorf(rx1 / IMG_W_F * (float)W);
    int y1 = (int)floorf(ry1 / IMG_H_F * (float)H);
    int x2 = (int)ceilf (rx2 / IMG_W_F * (float)W);
    int y2 = (int)ceilf (ry2 / IMG_H_F * (float)H);
    x1 = max(x1, 0);
    y1 = max(y1, 0);
    x2 = max(x2, 0);
    y2 = max(y2, 0);

    // Degenerate-box fixes, in reference order (x2 fix sees pre-clamp x1).
    if (x1 == 0 && x2 == 0) x2 = 1;
    if (y1 == 0 && y2 == 0) y2 = 1;
    if (x1 >= W) x1 = W - 1;
    if (y1 >= H) y1 = H - 1;

    // Mask is intersected with the [0,H) x [0,W) grid.
    const int ye = min(y2, H);
    const int xe = min(x2, W);

    const float* fb = feat + (size_t)b * C * H * W;
    float* ob = out + (size_t)bn * C;

    for (int c = threadIdx.x; c < C; c += blockDim.x) {
        const float* fc = fb + (size_t)c * H * W;
        float m = -INFINITY;
        for (int y = y1; y < ye; ++y) {
            const float* fr = fc + (size_t)y * W;
            for (int x = x1; x < xe; ++x) {
                m = fmaxf(m, fr[x]);
            }
        }
        ob[c] = m;   // coalesced across threads (consecutive c)
    }
}

extern "C" void kernel_launch(void* const* d_in, const int* in_sizes, int n_in,
                              void* d_out, int out_size, void* d_ws, size_t ws_size,
                              hipStream_t stream) {
    const int B = 2, C = 512, H = 50, W = 64, N = 128;

    const float* feat = (const float*)d_in[0];
    const float* rois = (const float*)d_in[1];
    float* out = (float*)d_out;

    dim3 grid(B * N);      // one block per ROI
    dim3 block(256);       // threads strided over C=512 (2 channels/thread)
    roipool_kernel<<<grid, block, 0, stream>>>(feat, rois, out, B, C, H, W, N);
}